// Round 2
// baseline (1581.734 us; speedup 1.0000x reference)
//
#include <hip/hip_runtime.h>

typedef unsigned short u16;
typedef __attribute__((ext_vector_type(8))) _Float16 f16x8;
typedef __attribute__((ext_vector_type(4))) float f32x4;

#define TOKENS 4096
#define SEQ    2048
#define DMODEL 1024
#define NHEAD  16
#define HDIM   64
#define FDIM   2048
#define NEXP   8
#define NSLOT  8192

__device__ __forceinline__ u16 f2h(float v) {
    _Float16 h = (_Float16)v;
    union { _Float16 f; u16 u; } c; c.f = h; return c.u;
}
__device__ __forceinline__ float h2f(u16 u) {
    union { u16 u; _Float16 f; } c; c.u = u; return (float)c.f;
}
__device__ __forceinline__ void split16(float v, u16& hi, u16& lo) {
    _Float16 h = (_Float16)v;
    float r = v - (float)h;
    _Float16 l = (_Float16)r;
    union { _Float16 f; u16 u; } a, b; a.f = h; b.f = l;
    hi = a.u; lo = b.u;
}

// ---------------------------------------------------------------------------
// Transpose + cast fp32 -> fp16 (optionally split hi/lo).
// out[rowMul*c + rowAdd][r] = in[r][c]   (c = src col, r = src row)
// ---------------------------------------------------------------------------
template<bool SPLIT_OUT>
__global__ __launch_bounds__(256) void transpose_cast(
    const float* __restrict__ in, u16* __restrict__ outh, u16* __restrict__ outl,
    int R, int C, long ibs, long obs, int rowMul, int rowAdd)
{
    __shared__ float tile[32][33];
    const int bc = blockIdx.x * 32, br = blockIdx.y * 32;
    const float* ip = in + (long)blockIdx.z * ibs;
    u16* oph = outh + (long)blockIdx.z * obs;
    u16* opl = SPLIT_OUT ? (outl + (long)blockIdx.z * obs) : nullptr;
    const int tx = threadIdx.x & 31, ty = threadIdx.x >> 5;
#pragma unroll
    for (int i = 0; i < 4; ++i)
        tile[ty + i*8][tx] = ip[(long)(br + ty + i*8) * C + bc + tx];
    __syncthreads();
#pragma unroll
    for (int i = 0; i < 4; ++i) {
        const int c = bc + ty + i*8;
        const long idx = (long)(rowMul * c + rowAdd) * R + br + tx;
        float v = tile[tx][ty + i*8];
        if (SPLIT_OUT) { u16 hi, lo; split16(v, hi, lo); oph[idx] = hi; opl[idx] = lo; }
        else oph[idx] = f2h(v);
    }
}

// ---------------------------------------------------------------------------
// RMSNorm: fp32 in -> fp16 hi (+optional fp16 lo)
// ---------------------------------------------------------------------------
__global__ __launch_bounds__(256) void rmsnorm_k(
    const float* __restrict__ x, const float* __restrict__ w,
    u16* __restrict__ oh, u16* __restrict__ ol)
{
    const int t = blockIdx.x;
    const int tid = threadIdx.x;
    const float* xr = x + (size_t)t * DMODEL;
    float4 v = *(const float4*)(xr + tid * 4);
    float ss = v.x*v.x + v.y*v.y + v.z*v.z + v.w*v.w;
#pragma unroll
    for (int off = 32; off; off >>= 1) ss += __shfl_xor(ss, off);
    __shared__ float red[4];
    if ((tid & 63) == 0) red[tid >> 6] = ss;
    __syncthreads();
    float tot = red[0] + red[1] + red[2] + red[3];
    float rms = rsqrtf(tot * (1.0f / DMODEL) + 1e-6f);
    float4 wv = *(const float4*)(w + tid * 4);
    float o0 = v.x * rms * wv.x, o1 = v.y * rms * wv.y;
    float o2 = v.z * rms * wv.z, o3 = v.w * rms * wv.w;
    u16 th[4], tl[4];
    split16(o0, th[0], tl[0]); split16(o1, th[1], tl[1]);
    split16(o2, th[2], tl[2]); split16(o3, th[3], tl[3]);
    const size_t base = (size_t)t * DMODEL + tid * 4;
    *(uint2*)(oh + base) = *(uint2*)th;
    if (ol) *(uint2*)(ol + base) = *(uint2*)tl;
}

// ---------------------------------------------------------------------------
// GEMM: C[M][N] = A[M][K] * B[K][N], B given transposed (BT[N][K]).
// fp16 MFMA 16x16x32, 128x128 tile, BK=32, 256 threads (4 waves, 64x64 each).
// SPLIT: A/B hi+lo pairs -> 3 MFMAs per tile (~fp32-quality product).
// OUTM: 0 = fp32 (+res if ADD_RES), 1 = fp16, 2 = fp16 split pair,
//       3 = fused silu(gate)*up -> fp16, gate/up interleaved in cols (N even),
//           output width N/2.
// EXPERT: blockIdx.z = expert; M from counts[], rows offset by bases[].
// INDIRECT: A row = idxl[e*TOKENS + r] (token gather).
// ---------------------------------------------------------------------------
template<bool SPLIT, int OUTM, bool ADD_RES, bool EXPERT, bool INDIRECT>
__global__ __launch_bounds__(256) void gemm_bt(
    const u16* __restrict__ Ah, const u16* __restrict__ Al,
    const u16* __restrict__ Bh, const u16* __restrict__ Bl,
    void* __restrict__ Ch, u16* __restrict__ Cl,
    const float* __restrict__ res,
    int M, int N, int K, long btStride,
    const int* __restrict__ counts, const int* __restrict__ bases,
    const int* __restrict__ idxl)
{
    constexpr int NS = SPLIT ? 2 : 1;
    const int tid = threadIdx.x;
    const int wave = tid >> 6, lane = tid & 63;
    const int quad = lane >> 4, lr = lane & 15;
    const int wm = wave >> 1, wn = wave & 1;

    int Me = M;
    long cbase = 0;
    const u16* bth = Bh;
    const u16* btl = Bl;
    if (EXPERT) {
        const int e = blockIdx.z;
        Me = counts[e];
        if ((int)blockIdx.y * 128 >= Me) return;
        cbase = bases[e];
        bth += (long)e * btStride;
        if (SPLIT) btl += (long)e * btStride;
    }
    const int rowBase = blockIdx.y * 128;
    const int colBase = blockIdx.x * 128;

    __shared__ __align__(16) u16 As[NS][128][40];
    __shared__ __align__(16) u16 Bs[NS][128][40];

    const u16* srcA[NS][2];
    const u16* srcB[NS][2];
    u16* dstA[2];
    u16* dstB[2];
#pragma unroll
    for (int q = 0; q < 2; ++q) {
        const int c = q * 256 + tid;
        const int rr = c >> 2;
        const int ko = (c & 3) * 8;
        dstA[q] = &As[0][rr][ko];
        dstB[q] = &Bs[0][rr][ko];
        int arg = rowBase + rr;
        if (EXPERT) arg = min(arg, Me - 1);
        long aRow;
        if (INDIRECT) aRow = idxl[(long)blockIdx.z * TOKENS + arg];
        else          aRow = cbase + arg;
        srcA[0][q] = Ah + aRow * (long)K + ko;
        srcB[0][q] = bth + (long)(colBase + rr) * K + ko;
        if (SPLIT) {
            srcA[NS-1][q] = Al + aRow * (long)K + ko;
            srcB[NS-1][q] = btl + (long)(colBase + rr) * K + ko;
        }
    }

    f32x4 acc[4][4];
    const f32x4 fz = {0.f, 0.f, 0.f, 0.f};
#pragma unroll
    for (int i = 0; i < 4; ++i)
#pragma unroll
        for (int j = 0; j < 4; ++j) acc[i][j] = fz;

    for (int k0 = 0; k0 < K; k0 += 32) {
        uint4 ra[NS][2], rb[NS][2];
#pragma unroll
        for (int s = 0; s < NS; ++s)
#pragma unroll
            for (int q = 0; q < 2; ++q) {
                ra[s][q] = *(const uint4*)srcA[s][q];
                rb[s][q] = *(const uint4*)srcB[s][q];
                srcA[s][q] += 32; srcB[s][q] += 32;
            }
        __syncthreads();
#pragma unroll
        for (int s = 0; s < NS; ++s)
#pragma unroll
            for (int q = 0; q < 2; ++q) {
                *(uint4*)(dstA[q] + s * 128 * 40) = ra[s][q];
                *(uint4*)(dstB[q] + s * 128 * 40) = rb[s][q];
            }
        __syncthreads();
        f16x8 af[NS][4], bfr[NS][4];
#pragma unroll
        for (int s = 0; s < NS; ++s) {
#pragma unroll
            for (int i = 0; i < 4; ++i)
                af[s][i] = *(const f16x8*)&As[s][wm*64 + i*16 + lr][quad*8];
#pragma unroll
            for (int j = 0; j < 4; ++j)
                bfr[s][j] = *(const f16x8*)&Bs[s][wn*64 + j*16 + lr][quad*8];
        }
#pragma unroll
        for (int i = 0; i < 4; ++i)
#pragma unroll
            for (int j = 0; j < 4; ++j) {
                acc[i][j] = __builtin_amdgcn_mfma_f32_16x16x32_f16(af[0][i], bfr[0][j], acc[i][j], 0, 0, 0);
                if (SPLIT) {
                    acc[i][j] = __builtin_amdgcn_mfma_f32_16x16x32_f16(af[0][i], bfr[NS-1][j], acc[i][j], 0, 0, 0);
                    acc[i][j] = __builtin_amdgcn_mfma_f32_16x16x32_f16(af[NS-1][i], bfr[0][j], acc[i][j], 0, 0, 0);
                }
            }
    }

#pragma unroll
    for (int i = 0; i < 4; ++i) {
#pragma unroll
        for (int j = 0; j < 4; ++j) {
            const int col = colBase + wn*64 + j*16 + lr;
#pragma unroll
            for (int r = 0; r < 4; ++r) {
                const int rowl = wm*64 + i*16 + quad*4 + r;
                const int grow = rowBase + rowl;
                float v = acc[i][j][r];
                if constexpr (OUTM == 3) {
                    // gate at even col, up at odd col; pair via adjacent lane
                    float p = __shfl_xor(v, 1);
                    if (EXPERT && grow >= Me) continue;
                    float g = (lr & 1) ? p : v;
                    float u = (lr & 1) ? v : p;
                    float o = g / (1.f + __expf(-g)) * u;
                    if (!(lr & 1)) {
                        const long idx = (cbase + grow) * (long)(N >> 1) + (col >> 1);
                        ((u16*)Ch)[idx] = f2h(o);
                    }
                    continue;
                }
                if (EXPERT && grow >= Me) continue;
                const long idx = (cbase + grow) * (long)N + col;
                if (ADD_RES) v += res[idx];
                if constexpr (OUTM == 0) {
                    ((float*)Ch)[idx] = v;
                } else if constexpr (OUTM == 1) {
                    ((u16*)Ch)[idx] = f2h(v);
                } else if constexpr (OUTM == 2) {
                    u16 hi, lo; split16(v, hi, lo);
                    ((u16*)Ch)[idx] = hi;
                    Cl[idx] = lo;
                }
            }
        }
    }
}

// ---------------------------------------------------------------------------
// Flash attention (causal). qkv layout per token: [q(1024)|k(1024)|v(1024)],
// head h at offset h*64. Split-fp16 inputs (hi/lo), fp32 softmax, split out.
// Block: 64 Q rows (4 waves x 16 rows), K/V tiles of 64. grid (32,16,2).
// ---------------------------------------------------------------------------
__global__ __launch_bounds__(256) void attn_k(
    const u16* __restrict__ qh_, const u16* __restrict__ ql_,
    u16* __restrict__ aoh, u16* __restrict__ aol)
{
    const int qb = blockIdx.x;
    const int h  = blockIdx.y;
    const int b  = blockIdx.z;
    const int tid = threadIdx.x;
    const int wave = tid >> 6, lane = tid & 63;
    const int quad = lane >> 4, lr = lane & 15;

    __shared__ __align__(16) u16 Kt[2][64][72];
    __shared__ __align__(16) u16 Vt[2][64][72];
    __shared__ __align__(16) u16 Pt[2][4][16][72];

    f16x8 qh[2], ql[2];
    {
        const size_t qoff = ((size_t)(b * SEQ + qb*64 + wave*16 + lr)) * 3072 + h * 64 + quad * 8;
        qh[0] = *(const f16x8*)(qh_ + qoff);
        qh[1] = *(const f16x8*)(qh_ + qoff + 32);
        ql[0] = *(const f16x8*)(ql_ + qoff);
        ql[1] = *(const f16x8*)(ql_ + qoff + 32);
    }
    const f32x4 fz = {0.f, 0.f, 0.f, 0.f};
    f32x4 accO[4];
#pragma unroll
    for (int nt = 0; nt < 4; ++nt) accO[nt] = fz;
    float mrow[4] = {-1e30f, -1e30f, -1e30f, -1e30f};
    float lrow[4] = {0.f, 0.f, 0.f, 0.f};
    const int ig0 = qb*64 + wave*16 + quad*4;

    for (int kb = 0; kb <= qb; ++kb) {
        // stage K (rows t, cols d) and V transposed (rows d, cols t), hi+lo
#pragma unroll
        for (int q = 0; q < 2; ++q) {
            const int c = q * 256 + tid;
            const int rr = c >> 3;
            const int off = (c & 7) * 8;
            const size_t basek = ((size_t)(b * SEQ + kb*64 + rr)) * 3072 + 1024 + h * 64 + off;
            *(uint4*)&Kt[0][rr][off] = *(const uint4*)(qh_ + basek);
            *(uint4*)&Kt[1][rr][off] = *(const uint4*)(ql_ + basek);
            u16 t8[8];
            *(uint4*)t8 = *(const uint4*)(qh_ + basek + 1024);
#pragma unroll
            for (int i = 0; i < 8; ++i) Vt[0][off + i][rr] = t8[i];
            *(uint4*)t8 = *(const uint4*)(ql_ + basek + 1024);
#pragma unroll
            for (int i = 0; i < 8; ++i) Vt[1][off + i][rr] = t8[i];
        }
        __syncthreads();

        // S = Q K^T (split product: hh + hl + lh)
        f32x4 accS[4];
#pragma unroll
        for (int nt = 0; nt < 4; ++nt) accS[nt] = fz;
#pragma unroll
        for (int ks = 0; ks < 2; ++ks) {
#pragma unroll
            for (int nt = 0; nt < 4; ++nt) {
                f16x8 kh = *(const f16x8*)&Kt[0][nt*16 + lr][ks*32 + quad*8];
                f16x8 kl = *(const f16x8*)&Kt[1][nt*16 + lr][ks*32 + quad*8];
                accS[nt] = __builtin_amdgcn_mfma_f32_16x16x32_f16(qh[ks], kh, accS[nt], 0, 0, 0);
                accS[nt] = __builtin_amdgcn_mfma_f32_16x16x32_f16(qh[ks], kl, accS[nt], 0, 0, 0);
                accS[nt] = __builtin_amdgcn_mfma_f32_16x16x32_f16(ql[ks], kh, accS[nt], 0, 0, 0);
            }
        }

        // scale + causal mask + online softmax (fp32)
        float pv[4][4];
        float mx[4] = {-1e30f, -1e30f, -1e30f, -1e30f};
        const bool diag = (kb == qb);
#pragma unroll
        for (int nt = 0; nt < 4; ++nt) {
            const int jg = kb*64 + nt*16 + lr;
#pragma unroll
            for (int r = 0; r < 4; ++r) {
                float s = accS[nt][r] * 0.125f;
                if (diag && jg > ig0 + r) s = -1e30f;
                pv[nt][r] = s;
                mx[r] = fmaxf(mx[r], s);
            }
        }
#pragma unroll
        for (int off = 1; off < 16; off <<= 1)
#pragma unroll
            for (int r = 0; r < 4; ++r) mx[r] = fmaxf(mx[r], __shfl_xor(mx[r], off));
        float alpha[4];
#pragma unroll
        for (int r = 0; r < 4; ++r) {
            float mn = fmaxf(mrow[r], mx[r]);
            alpha[r] = __expf(mrow[r] - mn);
            mrow[r] = mn;
        }
        float rs[4] = {0.f, 0.f, 0.f, 0.f};
#pragma unroll
        for (int nt = 0; nt < 4; ++nt)
#pragma unroll
            for (int r = 0; r < 4; ++r) {
                float p = __expf(pv[nt][r] - mrow[r]);
                pv[nt][r] = p;
                rs[r] += p;
            }
#pragma unroll
        for (int off = 1; off < 16; off <<= 1)
#pragma unroll
            for (int r = 0; r < 4; ++r) rs[r] += __shfl_xor(rs[r], off);
#pragma unroll
        for (int r = 0; r < 4; ++r) lrow[r] = lrow[r] * alpha[r] + rs[r];
#pragma unroll
        for (int nt = 0; nt < 4; ++nt)
#pragma unroll
            for (int r = 0; r < 4; ++r) accO[nt][r] *= alpha[r];

        // P (C-layout) -> LDS, split hi/lo, for A-operand reads
#pragma unroll
        for (int nt = 0; nt < 4; ++nt)
#pragma unroll
            for (int r = 0; r < 4; ++r) {
                u16 hi, lo; split16(pv[nt][r], hi, lo);
                Pt[0][wave][quad*4 + r][nt*16 + lr] = hi;
                Pt[1][wave][quad*4 + r][nt*16 + lr] = lo;
            }
        __syncthreads();

        // O += P V
#pragma unroll
        for (int ks = 0; ks < 2; ++ks) {
            f16x8 ph = *(const f16x8*)&Pt[0][wave][lr][ks*32 + quad*8];
            f16x8 pl = *(const f16x8*)&Pt[1][wave][lr][ks*32 + quad*8];
#pragma unroll
            for (int nt = 0; nt < 4; ++nt) {
                f16x8 vh = *(const f16x8*)&Vt[0][nt*16 + lr][ks*32 + quad*8];
                f16x8 vl = *(const f16x8*)&Vt[1][nt*16 + lr][ks*32 + quad*8];
                accO[nt] = __builtin_amdgcn_mfma_f32_16x16x32_f16(ph, vh, accO[nt], 0, 0, 0);
                accO[nt] = __builtin_amdgcn_mfma_f32_16x16x32_f16(ph, vl, accO[nt], 0, 0, 0);
                accO[nt] = __builtin_amdgcn_mfma_f32_16x16x32_f16(pl, vh, accO[nt], 0, 0, 0);
            }
        }
        __syncthreads();
    }

#pragma unroll
    for (int nt = 0; nt < 4; ++nt)
#pragma unroll
        for (int r = 0; r < 4; ++r) {
            const int t = ig0 + r;
            float o = accO[nt][r] / lrow[r];
            u16 hi, lo; split16(o, hi, lo);
            const size_t idx = ((size_t)(b * SEQ + t)) * DMODEL + h * 64 + nt*16 + lr;
            aoh[idx] = hi;
            aol[idx] = lo;
        }
}

// ---------------------------------------------------------------------------
// Router with inline RMSNorm: reads x1 fp32, computes rmsnorm(x1)*fnw in fp32,
// fp32 logits, top-2, normalized gates, per-expert token lists. 1 wave/token.
// ---------------------------------------------------------------------------
__global__ __launch_bounds__(64) void router_k(
    const float* __restrict__ x1, const float* __restrict__ fnw,
    const float* __restrict__ rw,
    int* __restrict__ count, int* __restrict__ tokE, int* __restrict__ tokP,
    float* __restrict__ tokG, int* __restrict__ idxl)
{
    const int t = blockIdx.x;
    const int lane = threadIdx.x;
    const float* xr = x1 + (size_t)t * DMODEL;
    float4 xv[4];
    float ss = 0.f;
#pragma unroll
    for (int it = 0; it < 4; ++it) {
        xv[it] = *(const float4*)(xr + (it * 64 + lane) * 4);
        ss += xv[it].x*xv[it].x + xv[it].y*xv[it].y + xv[it].z*xv[it].z + xv[it].w*xv[it].w;
    }
#pragma unroll
    for (int off = 32; off; off >>= 1) ss += __shfl_xor(ss, off);
    const float rms = rsqrtf(ss * (1.0f / DMODEL) + 1e-6f);

    float acc[NEXP];
#pragma unroll
    for (int e = 0; e < NEXP; ++e) acc[e] = 0.f;
#pragma unroll
    for (int it = 0; it < 4; ++it) {
        const int d0 = (it * 64 + lane) * 4;
        float4 wv = *(const float4*)(fnw + d0);
        float hvv[4] = {xv[it].x * rms * wv.x, xv[it].y * rms * wv.y,
                        xv[it].z * rms * wv.z, xv[it].w * rms * wv.w};
#pragma unroll
        for (int k = 0; k < 4; ++k) {
            const float* r = rw + (size_t)(d0 + k) * NEXP;
            float4 r0 = *(const float4*)(r);
            float4 r1 = *(const float4*)(r + 4);
            acc[0] += hvv[k] * r0.x; acc[1] += hvv[k] * r0.y;
            acc[2] += hvv[k] * r0.z; acc[3] += hvv[k] * r0.w;
            acc[4] += hvv[k] * r1.x; acc[5] += hvv[k] * r1.y;
            acc[6] += hvv[k] * r1.z; acc[7] += hvv[k] * r1.w;
        }
    }
#pragma unroll
    for (int e = 0; e < NEXP; ++e)
#pragma unroll
        for (int off = 32; off; off >>= 1) acc[e] += __shfl_down(acc[e], off);
    if (lane == 0) {
        int e0 = 0; float v0 = acc[0];
#pragma unroll
        for (int e = 1; e < NEXP; ++e) if (acc[e] > v0) { v0 = acc[e]; e0 = e; }
        int e1 = -1; float v1 = -3.4e38f;
#pragma unroll
        for (int e = 0; e < NEXP; ++e) if (e != e0 && acc[e] > v1) { v1 = acc[e]; e1 = e; }
        const float rexp = __expf(v1 - v0);
        const float g0 = 1.f / (1.f + rexp);
        const float g1 = rexp * g0;
        const int p0 = atomicAdd(&count[e0], 1);
        const int p1 = atomicAdd(&count[e1], 1);
        idxl[e0 * TOKENS + p0] = t;
        idxl[e1 * TOKENS + p1] = t;
        tokE[2*t] = e0; tokE[2*t + 1] = e1;
        tokP[2*t] = p0; tokP[2*t + 1] = p1;
        tokG[2*t] = g0; tokG[2*t + 1] = g1;
    }
}

__global__ void prefix_k(const int* __restrict__ count, int* __restrict__ base)
{
    if (threadIdx.x == 0) {
        int s = 0;
#pragma unroll
        for (int e = 0; e < NEXP; ++e) { base[e] = s; s += count[e]; }
    }
}

// out[t] = x1[t] + g0*y[slot0] + g1*y[slot1]; plus aux_loss = 0
__global__ __launch_bounds__(256) void combine_k(
    const float* __restrict__ x1, const u16* __restrict__ y,
    const int* __restrict__ tokE, const int* __restrict__ tokP,
    const float* __restrict__ tokG, const int* __restrict__ base,
    float* __restrict__ out)
{
    const int t = blockIdx.x;
    const int d = threadIdx.x * 4;
    const int e0 = tokE[2*t], e1 = tokE[2*t + 1];
    const int s0 = base[e0] + tokP[2*t], s1 = base[e1] + tokP[2*t + 1];
    const float g0 = tokG[2*t], g1 = tokG[2*t + 1];
    float4 xv = *(const float4*)(x1 + (size_t)t * DMODEL + d);
    u16 y0[4], y1[4];
    *(uint2*)y0 = *(const uint2*)(y + (size_t)s0 * DMODEL + d);
    *(uint2*)y1 = *(const uint2*)(y + (size_t)s1 * DMODEL + d);
    float4 o;
    o.x = xv.x + g0 * h2f(y0[0]) + g1 * h2f(y1[0]);
    o.y = xv.y + g0 * h2f(y0[1]) + g1 * h2f(y1[1]);
    o.z = xv.z + g0 * h2f(y0[2]) + g1 * h2f(y1[2]);
    o.w = xv.w + g0 * h2f(y0[3]) + g1 * h2f(y1[3]);
    *(float4*)(out + (size_t)t * DMODEL + d) = o;
    if (t == 0 && threadIdx.x == 0) out[(size_t)TOKENS * DMODEL] = 0.f;  // aux_loss (AUX_COEFF=0)
}

// ---------------------------------------------------------------------------
// Workspace arena (121 MB total), lifetime-overlaid:
//   [0,1)      ctl: counts/bases/tokE/tokP/tokG/idxl
//   [1,65)     hh(1-9) hl(9-17) qkvh(17-41) qkvl(41-65)
//                -> w13t(1-65) after attn
//                -> w2t(1-33) + yb(33-49) after MoE GEMM1
//   [65,97)    aoh(65-73) aol(73-81) qkvwt_h(81-87) qkvwt_l(87-93)
//              wo_h(93-95) wo_l(95-97)   -> upb(65-97) after out-proj
//   [97,113)   x1 (fp32, persists)
//   [113,121)  hnb (fp16 rmsnorm2, until GEMM1)
// ---------------------------------------------------------------------------
extern "C" void kernel_launch(void* const* d_in, const int* in_sizes, int n_in,
                              void* d_out, int out_size, void* d_ws, size_t ws_size,
                              hipStream_t stream)
{
    const float* x     = (const float*)d_in[0];
    const float* anw   = (const float*)d_in[1];
    const float* fnw   = (const float*)d_in[2];
    const float* qkv_w = (const float*)d_in[3];
    const float* out_w = (const float*)d_in[4];
    const float* rw    = (const float*)d_in[5];
    const float* w1    = (const float*)d_in[6];
    const float* w3    = (const float*)d_in[7];
    const float* w2    = (const float*)d_in[8];
    float* out = (float*)d_out;

    char* W = (char*)d_ws;
    const size_t MB = 1ull << 20;
    int*   counts = (int*)(W);
    int*   bases  = (int*)(W + 256);
    int*   tokE   = (int*)(W + 1024);
    int*   tokP   = (int*)(W + 1024 + 33*1024);
    float* tokG   = (float*)(W + 1024 + 66*1024);
    int*   idxl   = (int*)(W + 1024 + 99*1024);

    u16* hh      = (u16*)(W + 1*MB);
    u16* hl      = (u16*)(W + 9*MB);
    u16* qkvh    = (u16*)(W + 17*MB);
    u16* qkvl    = (u16*)(W + 41*MB);
    u16* aoh     = (u16*)(W + 65*MB);
    u16* aol     = (u16*)(W + 73*MB);
    u16* qkvwt_h = (u16*)(W + 81*MB);
    u16* qkvwt_l = (u16*)(W + 87*MB);
    u16* wo_h    = (u16*)(W + 93*MB);
    u16* wo_l    = (u16*)(W + 95*MB);
    float* x1    = (float*)(W + 97*MB);
    u16* hnb     = (u16*)(W + 113*MB);
    u16* w13t    = (u16*)(W + 1*MB);    // 64 MB, after attn
    u16* upb     = (u16*)(W + 65*MB);   // 32 MB, after out-proj
    u16* w2t     = (u16*)(W + 1*MB);    // 32 MB, after GEMM1
    u16* yb      = (u16*)(W + 33*MB);   // 16 MB, after GEMM1

    hipMemsetAsync(counts, 0, NEXP * 4, stream);

    // attn-path weight prep: transpose + split-cast
    transpose_cast<true ><<<dim3(96, 32, 1), 256, 0, stream>>>(qkv_w, qkvwt_h, qkvwt_l, 1024, 3072, 0, 0, 1, 0);
    transpose_cast<true ><<<dim3(32, 32, 1), 256, 0, stream>>>(out_w, wo_h, wo_l, 1024, 1024, 0, 0, 1, 0);

    // attention path (split-fp16 ~ fp32 quality; router selection depends on it)
    rmsnorm_k<<<TOKENS, 256, 0, stream>>>(x, anw, hh, hl);
    gemm_bt<true, 2, false, false, false><<<dim3(24, 32, 1), 256, 0, stream>>>(
        hh, hl, qkvwt_h, qkvwt_l, qkvh, qkvl, nullptr, TOKENS, 3072, 1024, 0, nullptr, nullptr, nullptr);
    attn_k<<<dim3(32, 16, 2), 256, 0, stream>>>(qkvh, qkvl, aoh, aol);

    // MoE weight prep into [1,65) — hh/hl/qkvh/qkvl are dead now.
    // Interleave: w1 col f -> row 2f (gate), w3 col f -> row 2f+1 (up).
    transpose_cast<false><<<dim3(64, 32, 8), 256, 0, stream>>>(w1, w13t, nullptr, 1024, 2048, 2048L*1024, 4096L*1024, 2, 0);
    transpose_cast<false><<<dim3(64, 32, 8), 256, 0, stream>>>(w3, w13t, nullptr, 1024, 2048, 2048L*1024, 4096L*1024, 2, 1);

    // out-proj + residual -> x1 (fp32)
    gemm_bt<true, 0, true, false, false><<<dim3(8, 32, 1), 256, 0, stream>>>(
        aoh, aol, wo_h, wo_l, x1, nullptr, x, TOKENS, 1024, 1024, 0, nullptr, nullptr, nullptr);

    // rmsnorm2 (fp16 for MoE) + fp32 router (inline rmsnorm)
    rmsnorm_k<<<TOKENS, 256, 0, stream>>>(x1, fnw, hnb, nullptr);
    router_k<<<TOKENS, 64, 0, stream>>>(x1, fnw, rw, counts, tokE, tokP, tokG, idxl);
    prefix_k<<<1, 64, 0, stream>>>(counts, bases);

    // MoE GEMM1 fused silu: (hnb gather) @ w13t -> upb (fp16, [slot][2048])
    gemm_bt<false, 3, false, true, true><<<dim3(32, 32, 8), 256, 0, stream>>>(
        hnb, nullptr, w13t, nullptr, upb, nullptr, nullptr, TOKENS, 4096, 1024, 4096L*1024, counts, bases, idxl);

    // w2 transpose into [1,33) — w13t dead now
    transpose_cast<false><<<dim3(32, 64, 8), 256, 0, stream>>>(w2, w2t, nullptr, 2048, 1024, 2048L*1024, 1024L*2048, 1, 0);

    // MoE GEMM2: upb @ w2t -> yb (fp16)
    gemm_bt<false, 1, false, true, false><<<dim3(8, 32, 8), 256, 0, stream>>>(
        upb, nullptr, w2t, nullptr, yb, nullptr, nullptr, TOKENS, 1024, 2048, 1024L*2048, counts, bases, idxl);

    combine_k<<<TOKENS, 256, 0, stream>>>(x1, yb, tokE, tokP, tokG, bases, out);
}

// Round 3
// 1003.641 us; speedup vs baseline: 1.5760x; 1.5760x over previous
//
#include <hip/hip_runtime.h>

typedef unsigned short u16;
typedef __attribute__((ext_vector_type(8))) _Float16 f16x8;
typedef __attribute__((ext_vector_type(4))) float f32x4;

#define TOKENS 4096
#define SEQ    2048
#define DMODEL 1024
#define NHEAD  16
#define HDIM   64
#define FDIM   2048
#define NEXP   8
#define NSLOT  8192

__device__ __forceinline__ u16 f2h(float v) {
    _Float16 h = (_Float16)v;
    union { _Float16 f; u16 u; } c; c.f = h; return c.u;
}
__device__ __forceinline__ float h2f(u16 u) {
    union { u16 u; _Float16 f; } c; c.u = u; return (float)c.f;
}
__device__ __forceinline__ void split16(float v, u16& hi, u16& lo) {
    _Float16 h = (_Float16)v;
    float r = v - (float)h;
    _Float16 l = (_Float16)r;
    union { _Float16 f; u16 u; } a, b; a.f = h; b.f = l;
    hi = a.u; lo = b.u;
}
// async global->LDS, 16 B per lane; LDS dest is wave-uniform base + lane*16
__device__ __forceinline__ void gld16(const u16* g, u16* l) {
    __builtin_amdgcn_global_load_lds(
        (const __attribute__((address_space(1))) void*)g,
        (__attribute__((address_space(3))) void*)l, 16, 0, 0);
}

// ---------------------------------------------------------------------------
// Transpose + cast fp32 -> fp16 (optionally split hi/lo).
// out[rowMul*c + rowAdd][r] = in[r][c]   (c = src col, r = src row)
// ---------------------------------------------------------------------------
template<bool SPLIT_OUT>
__global__ __launch_bounds__(256) void transpose_cast(
    const float* __restrict__ in, u16* __restrict__ outh, u16* __restrict__ outl,
    int R, int C, long ibs, long obs, int rowMul, int rowAdd)
{
    __shared__ float tile[32][33];
    const int bc = blockIdx.x * 32, br = blockIdx.y * 32;
    const float* ip = in + (long)blockIdx.z * ibs;
    u16* oph = outh + (long)blockIdx.z * obs;
    u16* opl = SPLIT_OUT ? (outl + (long)blockIdx.z * obs) : nullptr;
    const int tx = threadIdx.x & 31, ty = threadIdx.x >> 5;
#pragma unroll
    for (int i = 0; i < 4; ++i)
        tile[ty + i*8][tx] = ip[(long)(br + ty + i*8) * C + bc + tx];
    __syncthreads();
#pragma unroll
    for (int i = 0; i < 4; ++i) {
        const int c = bc + ty + i*8;
        const long idx = (long)(rowMul * c + rowAdd) * R + br + tx;
        float v = tile[tx][ty + i*8];
        if (SPLIT_OUT) { u16 hi, lo; split16(v, hi, lo); oph[idx] = hi; opl[idx] = lo; }
        else oph[idx] = f2h(v);
    }
}

// ---------------------------------------------------------------------------
// RMSNorm: fp32 in -> fp16 hi (+optional fp16 lo)
// ---------------------------------------------------------------------------
__global__ __launch_bounds__(256) void rmsnorm_k(
    const float* __restrict__ x, const float* __restrict__ w,
    u16* __restrict__ oh, u16* __restrict__ ol)
{
    const int t = blockIdx.x;
    const int tid = threadIdx.x;
    const float* xr = x + (size_t)t * DMODEL;
    float4 v = *(const float4*)(xr + tid * 4);
    float ss = v.x*v.x + v.y*v.y + v.z*v.z + v.w*v.w;
#pragma unroll
    for (int off = 32; off; off >>= 1) ss += __shfl_xor(ss, off);
    __shared__ float red[4];
    if ((tid & 63) == 0) red[tid >> 6] = ss;
    __syncthreads();
    float tot = red[0] + red[1] + red[2] + red[3];
    float rms = rsqrtf(tot * (1.0f / DMODEL) + 1e-6f);
    float4 wv = *(const float4*)(w + tid * 4);
    float o0 = v.x * rms * wv.x, o1 = v.y * rms * wv.y;
    float o2 = v.z * rms * wv.z, o3 = v.w * rms * wv.w;
    u16 th[4], tl[4];
    split16(o0, th[0], tl[0]); split16(o1, th[1], tl[1]);
    split16(o2, th[2], tl[2]); split16(o3, th[3], tl[3]);
    const size_t base = (size_t)t * DMODEL + tid * 4;
    *(uint2*)(oh + base) = *(uint2*)th;
    if (ol) *(uint2*)(ol + base) = *(uint2*)tl;
}

// ---------------------------------------------------------------------------
// GEMM: C[M][N] = A[M][K] * B[K][N], B given transposed (BT[N][K]).
// fp16 MFMA 16x16x32, 128x128 tile, BK=32, 256 threads (4 waves, 64x64 each).
// Staging: global_load_lds width=16 into unpadded [128][32] tiles with XOR
// swizzle (chunk p of row r holds global k-chunk p^((r>>1)&3)); fragment
// reads use ko=(quad^((lr>>1)&3))*8 -> 8 distinct b128/bank-group (minimum).
// SPLIT: A/B hi+lo pairs -> 3 MFMAs per tile (~fp32-quality product).
// OUTM: 0 = fp32 (+res if ADD_RES), 1 = fp16, 2 = fp16 split pair,
//       3 = fused silu(gate)*up -> fp16, gate/up interleaved cols, out N/2.
// EXPERT: blockIdx.z = expert; M from counts[], rows offset by bases[].
// INDIRECT: A row = idxl[e*TOKENS + r] (token gather).
// ---------------------------------------------------------------------------
template<bool SPLIT, int OUTM, bool ADD_RES, bool EXPERT, bool INDIRECT>
__global__ __launch_bounds__(256) void gemm_bt(
    const u16* __restrict__ Ah, const u16* __restrict__ Al,
    const u16* __restrict__ Bh, const u16* __restrict__ Bl,
    void* __restrict__ Ch, u16* __restrict__ Cl,
    const float* __restrict__ res,
    int M, int N, int K, long btStride,
    const int* __restrict__ counts, const int* __restrict__ bases,
    const int* __restrict__ idxl)
{
    constexpr int NS = SPLIT ? 2 : 1;
    const int tid = threadIdx.x;
    const int wave = tid >> 6, lane = tid & 63;
    const int quad = lane >> 4, lr = lane & 15;
    const int wm = wave >> 1, wn = wave & 1;

    int Me = M;
    long cbase = 0;
    const u16* bth = Bh;
    const u16* btl = Bl;
    if (EXPERT) {
        const int e = blockIdx.z;
        Me = counts[e];
        if ((int)blockIdx.y * 128 >= Me) return;
        cbase = bases[e];
        bth += (long)e * btStride;
        if (SPLIT) btl += (long)e * btStride;
    }
    const int rowBase = blockIdx.y * 128;
    const int colBase = blockIdx.x * 128;

    __shared__ __align__(16) u16 As[NS][128][32];
    __shared__ __align__(16) u16 Bs[NS][128][32];

    const u16* srcA[NS][2];
    const u16* srcB[NS][2];
    u16* ldsA[2];
    u16* ldsB[2];
#pragma unroll
    for (int q = 0; q < 2; ++q) {
        const int c = q * 256 + tid;
        const int rr = c >> 2;
        const int pg = (c & 3) ^ ((rr >> 1) & 3);   // swizzled global k-chunk
        const int ko = pg * 8;
        const int chunk0 = q * 256 + wave * 64;      // wave-uniform LDS chunk base
        ldsA[q] = &As[0][0][0] + (size_t)chunk0 * 8;
        ldsB[q] = &Bs[0][0][0] + (size_t)chunk0 * 8;
        int arg = rowBase + rr;
        if (EXPERT) arg = min(arg, Me - 1);
        long aRow;
        if (INDIRECT) aRow = idxl[(long)blockIdx.z * TOKENS + arg];
        else          aRow = cbase + arg;
        srcA[0][q] = Ah + aRow * (long)K + ko;
        srcB[0][q] = bth + (long)(colBase + rr) * K + ko;
        if (SPLIT) {
            srcA[NS-1][q] = Al + aRow * (long)K + ko;
            srcB[NS-1][q] = btl + (long)(colBase + rr) * K + ko;
        }
    }

    f32x4 acc[4][4];
    const f32x4 fz = {0.f, 0.f, 0.f, 0.f};
#pragma unroll
    for (int i = 0; i < 4; ++i)
#pragma unroll
        for (int j = 0; j < 4; ++j) acc[i][j] = fz;

    const int swz = (lr >> 1) & 3;   // row-dependent k-chunk swizzle for reads
    const int koA = ((quad ^ swz) * 8);

    for (int k0 = 0; k0 < K; k0 += 32) {
#pragma unroll
        for (int s = 0; s < NS; ++s)
#pragma unroll
            for (int q = 0; q < 2; ++q) {
                gld16(srcA[s][q], ldsA[q] + s * 128 * 32);
                gld16(srcB[s][q], ldsB[q] + s * 128 * 32);
                srcA[s][q] += 32; srcB[s][q] += 32;
            }
        __syncthreads();   // drains vmcnt(0): LDS tiles complete
        f16x8 af[NS][4], bfr[NS][4];
#pragma unroll
        for (int s = 0; s < NS; ++s) {
#pragma unroll
            for (int i = 0; i < 4; ++i)
                af[s][i] = *(const f16x8*)&As[s][wm*64 + i*16 + lr][koA];
#pragma unroll
            for (int j = 0; j < 4; ++j)
                bfr[s][j] = *(const f16x8*)&Bs[s][wn*64 + j*16 + lr][koA];
        }
#pragma unroll
        for (int i = 0; i < 4; ++i)
#pragma unroll
            for (int j = 0; j < 4; ++j) {
                acc[i][j] = __builtin_amdgcn_mfma_f32_16x16x32_f16(af[0][i], bfr[0][j], acc[i][j], 0, 0, 0);
                if (SPLIT) {
                    acc[i][j] = __builtin_amdgcn_mfma_f32_16x16x32_f16(af[0][i], bfr[NS-1][j], acc[i][j], 0, 0, 0);
                    acc[i][j] = __builtin_amdgcn_mfma_f32_16x16x32_f16(af[NS-1][i], bfr[0][j], acc[i][j], 0, 0, 0);
                }
            }
        __syncthreads();   // protect LDS before next iteration's staging
    }

#pragma unroll
    for (int i = 0; i < 4; ++i) {
#pragma unroll
        for (int j = 0; j < 4; ++j) {
            const int col = colBase + wn*64 + j*16 + lr;
#pragma unroll
            for (int r = 0; r < 4; ++r) {
                const int rowl = wm*64 + i*16 + quad*4 + r;
                const int grow = rowBase + rowl;
                float v = acc[i][j][r];
                if constexpr (OUTM == 3) {
                    // gate at even col, up at odd col; pair via adjacent lane
                    float p = __shfl_xor(v, 1);
                    if (EXPERT && grow >= Me) continue;
                    float g = (lr & 1) ? p : v;
                    float u = (lr & 1) ? v : p;
                    float o = g / (1.f + __expf(-g)) * u;
                    if (!(lr & 1)) {
                        const long idx = (cbase + grow) * (long)(N >> 1) + (col >> 1);
                        ((u16*)Ch)[idx] = f2h(o);
                    }
                    continue;
                }
                if (EXPERT && grow >= Me) continue;
                const long idx = (cbase + grow) * (long)N + col;
                if (ADD_RES) v += res[idx];
                if constexpr (OUTM == 0) {
                    ((float*)Ch)[idx] = v;
                } else if constexpr (OUTM == 1) {
                    ((u16*)Ch)[idx] = f2h(v);
                } else if constexpr (OUTM == 2) {
                    u16 hi, lo; split16(v, hi, lo);
                    ((u16*)Ch)[idx] = hi;
                    Cl[idx] = lo;
                }
            }
        }
    }
}

// ---------------------------------------------------------------------------
// Flash attention (causal). qkv layout per token: [q(1024)|k(1024)|v(1024)],
// head h at offset h*64. Split-fp16 inputs (hi/lo), fp32 softmax, split out.
// Block: 64 Q rows (4 waves x 16 rows), K/V tiles of 64. grid (32,16,2).
// ---------------------------------------------------------------------------
__global__ __launch_bounds__(256) void attn_k(
    const u16* __restrict__ qh_, const u16* __restrict__ ql_,
    u16* __restrict__ aoh, u16* __restrict__ aol)
{
    const int qb = blockIdx.x;
    const int h  = blockIdx.y;
    const int b  = blockIdx.z;
    const int tid = threadIdx.x;
    const int wave = tid >> 6, lane = tid & 63;
    const int quad = lane >> 4, lr = lane & 15;

    __shared__ __align__(16) u16 Kt[2][64][72];
    __shared__ __align__(16) u16 Vt[2][64][72];
    __shared__ __align__(16) u16 Pt[2][4][16][72];

    f16x8 qh[2], ql[2];
    {
        const size_t qoff = ((size_t)(b * SEQ + qb*64 + wave*16 + lr)) * 3072 + h * 64 + quad * 8;
        qh[0] = *(const f16x8*)(qh_ + qoff);
        qh[1] = *(const f16x8*)(qh_ + qoff + 32);
        ql[0] = *(const f16x8*)(ql_ + qoff);
        ql[1] = *(const f16x8*)(ql_ + qoff + 32);
    }
    const f32x4 fz = {0.f, 0.f, 0.f, 0.f};
    f32x4 accO[4];
#pragma unroll
    for (int nt = 0; nt < 4; ++nt) accO[nt] = fz;
    float mrow[4] = {-1e30f, -1e30f, -1e30f, -1e30f};
    float lrow[4] = {0.f, 0.f, 0.f, 0.f};
    const int ig0 = qb*64 + wave*16 + quad*4;

    for (int kb = 0; kb <= qb; ++kb) {
        // stage K (rows t, cols d) and V transposed (rows d, cols t), hi+lo
#pragma unroll
        for (int q = 0; q < 2; ++q) {
            const int c = q * 256 + tid;
            const int rr = c >> 3;
            const int off = (c & 7) * 8;
            const size_t basek = ((size_t)(b * SEQ + kb*64 + rr)) * 3072 + 1024 + h * 64 + off;
            *(uint4*)&Kt[0][rr][off] = *(const uint4*)(qh_ + basek);
            *(uint4*)&Kt[1][rr][off] = *(const uint4*)(ql_ + basek);
            u16 t8[8];
            *(uint4*)t8 = *(const uint4*)(qh_ + basek + 1024);
#pragma unroll
            for (int i = 0; i < 8; ++i) Vt[0][off + i][rr] = t8[i];
            *(uint4*)t8 = *(const uint4*)(ql_ + basek + 1024);
#pragma unroll
            for (int i = 0; i < 8; ++i) Vt[1][off + i][rr] = t8[i];
        }
        __syncthreads();

        // S = Q K^T (split product: hh + hl + lh)
        f32x4 accS[4];
#pragma unroll
        for (int nt = 0; nt < 4; ++nt) accS[nt] = fz;
#pragma unroll
        for (int ks = 0; ks < 2; ++ks) {
#pragma unroll
            for (int nt = 0; nt < 4; ++nt) {
                f16x8 kh = *(const f16x8*)&Kt[0][nt*16 + lr][ks*32 + quad*8];
                f16x8 kl = *(const f16x8*)&Kt[1][nt*16 + lr][ks*32 + quad*8];
                accS[nt] = __builtin_amdgcn_mfma_f32_16x16x32_f16(qh[ks], kh, accS[nt], 0, 0, 0);
                accS[nt] = __builtin_amdgcn_mfma_f32_16x16x32_f16(qh[ks], kl, accS[nt], 0, 0, 0);
                accS[nt] = __builtin_amdgcn_mfma_f32_16x16x32_f16(ql[ks], kh, accS[nt], 0, 0, 0);
            }
        }

        // scale + causal mask + online softmax (fp32)
        float pv[4][4];
        float mx[4] = {-1e30f, -1e30f, -1e30f, -1e30f};
        const bool diag = (kb == qb);
#pragma unroll
        for (int nt = 0; nt < 4; ++nt) {
            const int jg = kb*64 + nt*16 + lr;
#pragma unroll
            for (int r = 0; r < 4; ++r) {
                float s = accS[nt][r] * 0.125f;
                if (diag && jg > ig0 + r) s = -1e30f;
                pv[nt][r] = s;
                mx[r] = fmaxf(mx[r], s);
            }
        }
#pragma unroll
        for (int off = 1; off < 16; off <<= 1)
#pragma unroll
            for (int r = 0; r < 4; ++r) mx[r] = fmaxf(mx[r], __shfl_xor(mx[r], off));
        float alpha[4];
#pragma unroll
        for (int r = 0; r < 4; ++r) {
            float mn = fmaxf(mrow[r], mx[r]);
            alpha[r] = __expf(mrow[r] - mn);
            mrow[r] = mn;
        }
        float rs[4] = {0.f, 0.f, 0.f, 0.f};
#pragma unroll
        for (int nt = 0; nt < 4; ++nt)
#pragma unroll
            for (int r = 0; r < 4; ++r) {
                float p = __expf(pv[nt][r] - mrow[r]);
                pv[nt][r] = p;
                rs[r] += p;
            }
#pragma unroll
        for (int off = 1; off < 16; off <<= 1)
#pragma unroll
            for (int r = 0; r < 4; ++r) rs[r] += __shfl_xor(rs[r], off);
#pragma unroll
        for (int r = 0; r < 4; ++r) lrow[r] = lrow[r] * alpha[r] + rs[r];
#pragma unroll
        for (int nt = 0; nt < 4; ++nt)
#pragma unroll
            for (int r = 0; r < 4; ++r) accO[nt][r] *= alpha[r];

        // P (C-layout) -> LDS, split hi/lo, for A-operand reads
#pragma unroll
        for (int nt = 0; nt < 4; ++nt)
#pragma unroll
            for (int r = 0; r < 4; ++r) {
                u16 hi, lo; split16(pv[nt][r], hi, lo);
                Pt[0][wave][quad*4 + r][nt*16 + lr] = hi;
                Pt[1][wave][quad*4 + r][nt*16 + lr] = lo;
            }
        __syncthreads();

        // O += P V
#pragma unroll
        for (int ks = 0; ks < 2; ++ks) {
            f16x8 ph = *(const f16x8*)&Pt[0][wave][lr][ks*32 + quad*8];
            f16x8 pl = *(const f16x8*)&Pt[1][wave][lr][ks*32 + quad*8];
#pragma unroll
            for (int nt = 0; nt < 4; ++nt) {
                f16x8 vh = *(const f16x8*)&Vt[0][nt*16 + lr][ks*32 + quad*8];
                f16x8 vl = *(const f16x8*)&Vt[1][nt*16 + lr][ks*32 + quad*8];
                accO[nt] = __builtin_amdgcn_mfma_f32_16x16x32_f16(ph, vh, accO[nt], 0, 0, 0);
                accO[nt] = __builtin_amdgcn_mfma_f32_16x16x32_f16(ph, vl, accO[nt], 0, 0, 0);
                accO[nt] = __builtin_amdgcn_mfma_f32_16x16x32_f16(pl, vh, accO[nt], 0, 0, 0);
            }
        }
        __syncthreads();
    }

#pragma unroll
    for (int nt = 0; nt < 4; ++nt)
#pragma unroll
        for (int r = 0; r < 4; ++r) {
            const int t = ig0 + r;
            float o = accO[nt][r] / lrow[r];
            u16 hi, lo; split16(o, hi, lo);
            const size_t idx = ((size_t)(b * SEQ + t)) * DMODEL + h * 64 + nt*16 + lr;
            aoh[idx] = hi;
            aol[idx] = lo;
        }
}

// ---------------------------------------------------------------------------
// Router with inline RMSNorm: reads x1 fp32, computes rmsnorm(x1)*fnw in fp32,
// fp32 logits, top-2, normalized gates, per-expert token lists. 1 wave/token.
// ---------------------------------------------------------------------------
__global__ __launch_bounds__(64) void router_k(
    const float* __restrict__ x1, const float* __restrict__ fnw,
    const float* __restrict__ rw,
    int* __restrict__ count, int* __restrict__ tokE, int* __restrict__ tokP,
    float* __restrict__ tokG, int* __restrict__ idxl)
{
    const int t = blockIdx.x;
    const int lane = threadIdx.x;
    const float* xr = x1 + (size_t)t * DMODEL;
    float4 xv[4];
    float ss = 0.f;
#pragma unroll
    for (int it = 0; it < 4; ++it) {
        xv[it] = *(const float4*)(xr + (it * 64 + lane) * 4);
        ss += xv[it].x*xv[it].x + xv[it].y*xv[it].y + xv[it].z*xv[it].z + xv[it].w*xv[it].w;
    }
#pragma unroll
    for (int off = 32; off; off >>= 1) ss += __shfl_xor(ss, off);
    const float rms = rsqrtf(ss * (1.0f / DMODEL) + 1e-6f);

    float acc[NEXP];
#pragma unroll
    for (int e = 0; e < NEXP; ++e) acc[e] = 0.f;
#pragma unroll
    for (int it = 0; it < 4; ++it) {
        const int d0 = (it * 64 + lane) * 4;
        float4 wv = *(const float4*)(fnw + d0);
        float hvv[4] = {xv[it].x * rms * wv.x, xv[it].y * rms * wv.y,
                        xv[it].z * rms * wv.z, xv[it].w * rms * wv.w};
#pragma unroll
        for (int k = 0; k < 4; ++k) {
            const float* r = rw + (size_t)(d0 + k) * NEXP;
            float4 r0 = *(const float4*)(r);
            float4 r1 = *(const float4*)(r + 4);
            acc[0] += hvv[k] * r0.x; acc[1] += hvv[k] * r0.y;
            acc[2] += hvv[k] * r0.z; acc[3] += hvv[k] * r0.w;
            acc[4] += hvv[k] * r1.x; acc[5] += hvv[k] * r1.y;
            acc[6] += hvv[k] * r1.z; acc[7] += hvv[k] * r1.w;
        }
    }
#pragma unroll
    for (int e = 0; e < NEXP; ++e)
#pragma unroll
        for (int off = 32; off; off >>= 1) acc[e] += __shfl_down(acc[e], off);
    if (lane == 0) {
        int e0 = 0; float v0 = acc[0];
#pragma unroll
        for (int e = 1; e < NEXP; ++e) if (acc[e] > v0) { v0 = acc[e]; e0 = e; }
        int e1 = -1; float v1 = -3.4e38f;
#pragma unroll
        for (int e = 0; e < NEXP; ++e) if (e != e0 && acc[e] > v1) { v1 = acc[e]; e1 = e; }
        const float rexp = __expf(v1 - v0);
        const float g0 = 1.f / (1.f + rexp);
        const float g1 = rexp * g0;
        const int p0 = atomicAdd(&count[e0], 1);
        const int p1 = atomicAdd(&count[e1], 1);
        idxl[e0 * TOKENS + p0] = t;
        idxl[e1 * TOKENS + p1] = t;
        tokE[2*t] = e0; tokE[2*t + 1] = e1;
        tokP[2*t] = p0; tokP[2*t + 1] = p1;
        tokG[2*t] = g0; tokG[2*t + 1] = g1;
    }
}

__global__ void prefix_k(const int* __restrict__ count, int* __restrict__ base)
{
    if (threadIdx.x == 0) {
        int s = 0;
#pragma unroll
        for (int e = 0; e < NEXP; ++e) { base[e] = s; s += count[e]; }
    }
}

// out[t] = x1[t] + g0*y[slot0] + g1*y[slot1]; plus aux_loss = 0
__global__ __launch_bounds__(256) void combine_k(
    const float* __restrict__ x1, const u16* __restrict__ y,
    const int* __restrict__ tokE, const int* __restrict__ tokP,
    const float* __restrict__ tokG, const int* __restrict__ base,
    float* __restrict__ out)
{
    const int t = blockIdx.x;
    const int d = threadIdx.x * 4;
    const int e0 = tokE[2*t], e1 = tokE[2*t + 1];
    const int s0 = base[e0] + tokP[2*t], s1 = base[e1] + tokP[2*t + 1];
    const float g0 = tokG[2*t], g1 = tokG[2*t + 1];
    float4 xv = *(const float4*)(x1 + (size_t)t * DMODEL + d);
    u16 y0[4], y1[4];
    *(uint2*)y0 = *(const uint2*)(y + (size_t)s0 * DMODEL + d);
    *(uint2*)y1 = *(const uint2*)(y + (size_t)s1 * DMODEL + d);
    float4 o;
    o.x = xv.x + g0 * h2f(y0[0]) + g1 * h2f(y1[0]);
    o.y = xv.y + g0 * h2f(y0[1]) + g1 * h2f(y1[1]);
    o.z = xv.z + g0 * h2f(y0[2]) + g1 * h2f(y1[2]);
    o.w = xv.w + g0 * h2f(y0[3]) + g1 * h2f(y1[3]);
    *(float4*)(out + (size_t)t * DMODEL + d) = o;
    if (t == 0 && threadIdx.x == 0) out[(size_t)TOKENS * DMODEL] = 0.f;  // aux_loss (AUX_COEFF=0)
}

// ---------------------------------------------------------------------------
// Workspace arena (121 MB total), lifetime-overlaid:
//   [0,1)      ctl: counts/bases/tokE/tokP/tokG/idxl
//   [1,65)     hh(1-9) hl(9-17) qkvh(17-41) qkvl(41-65)
//                -> w13t(1-65) after attn
//                -> w2t(1-33) + yb(33-49) after MoE GEMM1
//   [65,97)    aoh(65-73) aol(73-81) qkvwt_h(81-87) qkvwt_l(87-93)
//              wo_h(93-95) wo_l(95-97)   -> upb(65-97) after out-proj
//   [97,113)   x1 (fp32, persists)
//   [113,121)  hnb (fp16 rmsnorm2, until GEMM1)
// ---------------------------------------------------------------------------
extern "C" void kernel_launch(void* const* d_in, const int* in_sizes, int n_in,
                              void* d_out, int out_size, void* d_ws, size_t ws_size,
                              hipStream_t stream)
{
    const float* x     = (const float*)d_in[0];
    const float* anw   = (const float*)d_in[1];
    const float* fnw   = (const float*)d_in[2];
    const float* qkv_w = (const float*)d_in[3];
    const float* out_w = (const float*)d_in[4];
    const float* rw    = (const float*)d_in[5];
    const float* w1    = (const float*)d_in[6];
    const float* w3    = (const float*)d_in[7];
    const float* w2    = (const float*)d_in[8];
    float* out = (float*)d_out;

    char* W = (char*)d_ws;
    const size_t MB = 1ull << 20;
    int*   counts = (int*)(W);
    int*   bases  = (int*)(W + 256);
    int*   tokE   = (int*)(W + 1024);
    int*   tokP   = (int*)(W + 1024 + 33*1024);
    float* tokG   = (float*)(W + 1024 + 66*1024);
    int*   idxl   = (int*)(W + 1024 + 99*1024);

    u16* hh      = (u16*)(W + 1*MB);
    u16* hl      = (u16*)(W + 9*MB);
    u16* qkvh    = (u16*)(W + 17*MB);
    u16* qkvl    = (u16*)(W + 41*MB);
    u16* aoh     = (u16*)(W + 65*MB);
    u16* aol     = (u16*)(W + 73*MB);
    u16* qkvwt_h = (u16*)(W + 81*MB);
    u16* qkvwt_l = (u16*)(W + 87*MB);
    u16* wo_h    = (u16*)(W + 93*MB);
    u16* wo_l    = (u16*)(W + 95*MB);
    float* x1    = (float*)(W + 97*MB);
    u16* hnb     = (u16*)(W + 113*MB);
    u16* w13t    = (u16*)(W + 1*MB);    // 64 MB, after attn
    u16* upb     = (u16*)(W + 65*MB);   // 32 MB, after out-proj
    u16* w2t     = (u16*)(W + 1*MB);    // 32 MB, after GEMM1
    u16* yb      = (u16*)(W + 33*MB);   // 16 MB, after GEMM1

    hipMemsetAsync(counts, 0, NEXP * 4, stream);

    // attn-path weight prep: transpose + split-cast
    transpose_cast<true ><<<dim3(96, 32, 1), 256, 0, stream>>>(qkv_w, qkvwt_h, qkvwt_l, 1024, 3072, 0, 0, 1, 0);
    transpose_cast<true ><<<dim3(32, 32, 1), 256, 0, stream>>>(out_w, wo_h, wo_l, 1024, 1024, 0, 0, 1, 0);

    // attention path (split-fp16 ~ fp32 quality; router selection depends on it)
    rmsnorm_k<<<TOKENS, 256, 0, stream>>>(x, anw, hh, hl);
    gemm_bt<true, 2, false, false, false><<<dim3(24, 32, 1), 256, 0, stream>>>(
        hh, hl, qkvwt_h, qkvwt_l, qkvh, qkvl, nullptr, TOKENS, 3072, 1024, 0, nullptr, nullptr, nullptr);
    attn_k<<<dim3(32, 16, 2), 256, 0, stream>>>(qkvh, qkvl, aoh, aol);

    // MoE weight prep into [1,65) — hh/hl/qkvh/qkvl are dead now.
    // Interleave: w1 col f -> row 2f (gate), w3 col f -> row 2f+1 (up).
    transpose_cast<false><<<dim3(64, 32, 8), 256, 0, stream>>>(w1, w13t, nullptr, 1024, 2048, 2048L*1024, 4096L*1024, 2, 0);
    transpose_cast<false><<<dim3(64, 32, 8), 256, 0, stream>>>(w3, w13t, nullptr, 1024, 2048, 2048L*1024, 4096L*1024, 2, 1);

    // out-proj + residual -> x1 (fp32)
    gemm_bt<true, 0, true, false, false><<<dim3(8, 32, 1), 256, 0, stream>>>(
        aoh, aol, wo_h, wo_l, x1, nullptr, x, TOKENS, 1024, 1024, 0, nullptr, nullptr, nullptr);

    // rmsnorm2 (fp16 for MoE) + fp32 router (inline rmsnorm)
    rmsnorm_k<<<TOKENS, 256, 0, stream>>>(x1, fnw, hnb, nullptr);
    router_k<<<TOKENS, 64, 0, stream>>>(x1, fnw, rw, counts, tokE, tokP, tokG, idxl);
    prefix_k<<<1, 64, 0, stream>>>(counts, bases);

    // MoE GEMM1 fused silu: (hnb gather) @ w13t -> upb (fp16, [slot][2048])
    gemm_bt<false, 3, false, true, true><<<dim3(32, 32, 8), 256, 0, stream>>>(
        hnb, nullptr, w13t, nullptr, upb, nullptr, nullptr, TOKENS, 4096, 1024, 4096L*1024, counts, bases, idxl);

    // w2 transpose into [1,33) — w13t dead now
    transpose_cast<false><<<dim3(32, 64, 8), 256, 0, stream>>>(w2, w2t, nullptr, 2048, 1024, 2048L*1024, 1024L*2048, 1, 0);

    // MoE GEMM2: upb @ w2t -> yb (fp16)
    gemm_bt<false, 1, false, true, false><<<dim3(8, 32, 8), 256, 0, stream>>>(
        upb, nullptr, w2t, nullptr, yb, nullptr, nullptr, TOKENS, 1024, 2048, 1024L*2048, counts, bases, idxl);

    combine_k<<<TOKENS, 256, 0, stream>>>(x1, yb, tokE, tokP, tokG, bases, out);
}

// Round 4
// 901.991 us; speedup vs baseline: 1.7536x; 1.1127x over previous
//
#include <hip/hip_runtime.h>

typedef unsigned short u16;
typedef __attribute__((ext_vector_type(8))) _Float16 f16x8;
typedef __attribute__((ext_vector_type(4))) float f32x4;

#define TOKENS 4096
#define SEQ    2048
#define DMODEL 1024
#define NHEAD  16
#define HDIM   64
#define FDIM   2048
#define NEXP   8
#define NSLOT  8192

__device__ __forceinline__ u16 f2h(float v) {
    _Float16 h = (_Float16)v;
    union { _Float16 f; u16 u; } c; c.f = h; return c.u;
}
__device__ __forceinline__ float h2f(u16 u) {
    union { u16 u; _Float16 f; } c; c.u = u; return (float)c.f;
}
__device__ __forceinline__ void split16(float v, u16& hi, u16& lo) {
    _Float16 h = (_Float16)v;
    float r = v - (float)h;
    _Float16 l = (_Float16)r;
    union { _Float16 f; u16 u; } a, b; a.f = h; b.f = l;
    hi = a.u; lo = b.u;
}
// async global->LDS, 16 B per lane; LDS dest is wave-uniform base + lane*16
__device__ __forceinline__ void gld16(const u16* g, u16* l) {
    __builtin_amdgcn_global_load_lds(
        (const __attribute__((address_space(1))) void*)g,
        (__attribute__((address_space(3))) void*)l, 16, 0, 0);
}

// ---------------------------------------------------------------------------
// Transpose + cast fp32 -> fp16 (optionally split hi/lo).
// out[rowMul*c + rowAdd][r] = in[r][c]   (c = src col, r = src row)
// ---------------------------------------------------------------------------
template<bool SPLIT_OUT>
__global__ __launch_bounds__(256) void transpose_cast(
    const float* __restrict__ in, u16* __restrict__ outh, u16* __restrict__ outl,
    int R, int C, long ibs, long obs, int rowMul, int rowAdd)
{
    __shared__ float tile[32][33];
    const int bc = blockIdx.x * 32, br = blockIdx.y * 32;
    const float* ip = in + (long)blockIdx.z * ibs;
    u16* oph = outh + (long)blockIdx.z * obs;
    u16* opl = SPLIT_OUT ? (outl + (long)blockIdx.z * obs) : nullptr;
    const int tx = threadIdx.x & 31, ty = threadIdx.x >> 5;
#pragma unroll
    for (int i = 0; i < 4; ++i)
        tile[ty + i*8][tx] = ip[(long)(br + ty + i*8) * C + bc + tx];
    __syncthreads();
#pragma unroll
    for (int i = 0; i < 4; ++i) {
        const int c = bc + ty + i*8;
        const long idx = (long)(rowMul * c + rowAdd) * R + br + tx;
        float v = tile[tx][ty + i*8];
        if (SPLIT_OUT) { u16 hi, lo; split16(v, hi, lo); oph[idx] = hi; opl[idx] = lo; }
        else oph[idx] = f2h(v);
    }
}

// ---------------------------------------------------------------------------
// V transpose: v[b][t][h*64+d] (inside qkv at col 2048+) -> vt[(b,h)][d][t]
// for both hi and lo components. 32x32 LDS tiles.
// ---------------------------------------------------------------------------
__global__ __launch_bounds__(256) void vtrans_k(
    const u16* __restrict__ qh_, const u16* __restrict__ ql_,
    u16* __restrict__ vth, u16* __restrict__ vtl)
{
    __shared__ u16 tile[32][34];
    const int bt = blockIdx.x, bd = blockIdx.y, bh = blockIdx.z;
    const int b = bh >> 4, h = bh & 15;
    const int tx = threadIdx.x & 31, ty = threadIdx.x >> 5;
#pragma unroll
    for (int s = 0; s < 2; ++s) {
        const u16* sp = s ? ql_ : qh_;
        u16* dp = s ? vtl : vth;
        if (s) __syncthreads();
#pragma unroll
        for (int i = 0; i < 4; ++i) {
            const int t = bt*32 + ty + i*8;
            const int d = bd*32 + tx;
            tile[ty + i*8][tx] = sp[(size_t)(b*SEQ + t)*3072 + 2048 + h*64 + d];
        }
        __syncthreads();
#pragma unroll
        for (int i = 0; i < 4; ++i) {
            const int d = bd*32 + ty + i*8;
            const int t = bt*32 + tx;
            dp[((size_t)bh*64 + d)*2048 + t] = tile[tx][ty + i*8];
        }
    }
}

// ---------------------------------------------------------------------------
// RMSNorm: fp32 in -> fp16 hi (+optional fp16 lo)
// ---------------------------------------------------------------------------
__global__ __launch_bounds__(256) void rmsnorm_k(
    const float* __restrict__ x, const float* __restrict__ w,
    u16* __restrict__ oh, u16* __restrict__ ol)
{
    const int t = blockIdx.x;
    const int tid = threadIdx.x;
    const float* xr = x + (size_t)t * DMODEL;
    float4 v = *(const float4*)(xr + tid * 4);
    float ss = v.x*v.x + v.y*v.y + v.z*v.z + v.w*v.w;
#pragma unroll
    for (int off = 32; off; off >>= 1) ss += __shfl_xor(ss, off);
    __shared__ float red[4];
    if ((tid & 63) == 0) red[tid >> 6] = ss;
    __syncthreads();
    float tot = red[0] + red[1] + red[2] + red[3];
    float rms = rsqrtf(tot * (1.0f / DMODEL) + 1e-6f);
    float4 wv = *(const float4*)(w + tid * 4);
    float o0 = v.x * rms * wv.x, o1 = v.y * rms * wv.y;
    float o2 = v.z * rms * wv.z, o3 = v.w * rms * wv.w;
    u16 th[4], tl[4];
    split16(o0, th[0], tl[0]); split16(o1, th[1], tl[1]);
    split16(o2, th[2], tl[2]); split16(o3, th[3], tl[3]);
    const size_t base = (size_t)t * DMODEL + tid * 4;
    *(uint2*)(oh + base) = *(uint2*)th;
    if (ol) *(uint2*)(ol + base) = *(uint2*)tl;
}

// ---------------------------------------------------------------------------
// GEMM: C[M][N] = A[M][K] * B[K][N], B given transposed (BT[N][K]).
// fp16 MFMA 16x16x32, 128x128 tile, BK=32, 256 threads (4 waves, 64x64 each).
// Staging: global_load_lds width=16 into unpadded [128][32] tiles with XOR
// swizzle (chunk p of row r holds global k-chunk p^((r>>1)&3)); fragment
// reads use ko=(quad^((lr>>1)&3))*8 -> 8 distinct b128/bank-group (minimum).
// SPLIT: A/B hi+lo pairs -> 3 MFMAs per tile (~fp32-quality product).
// OUTM: 0 = fp32 (+res if ADD_RES), 1 = fp16, 2 = fp16 split pair,
//       3 = fused silu(gate)*up -> fp16, gate/up interleaved cols, out N/2.
// EXPERT: blockIdx.z = expert; M from counts[], rows offset by bases[].
// INDIRECT: A row = idxl[e*TOKENS + r] (token gather).
// ---------------------------------------------------------------------------
template<bool SPLIT, int OUTM, bool ADD_RES, bool EXPERT, bool INDIRECT>
__global__ __launch_bounds__(256) void gemm_bt(
    const u16* __restrict__ Ah, const u16* __restrict__ Al,
    const u16* __restrict__ Bh, const u16* __restrict__ Bl,
    void* __restrict__ Ch, u16* __restrict__ Cl,
    const float* __restrict__ res,
    int M, int N, int K, long btStride,
    const int* __restrict__ counts, const int* __restrict__ bases,
    const int* __restrict__ idxl)
{
    constexpr int NS = SPLIT ? 2 : 1;
    const int tid = threadIdx.x;
    const int wave = tid >> 6, lane = tid & 63;
    const int quad = lane >> 4, lr = lane & 15;
    const int wm = wave >> 1, wn = wave & 1;

    int Me = M;
    long cbase = 0;
    const u16* bth = Bh;
    const u16* btl = Bl;
    if (EXPERT) {
        const int e = blockIdx.z;
        Me = counts[e];
        if ((int)blockIdx.y * 128 >= Me) return;
        cbase = bases[e];
        bth += (long)e * btStride;
        if (SPLIT) btl += (long)e * btStride;
    }
    const int rowBase = blockIdx.y * 128;
    const int colBase = blockIdx.x * 128;

    __shared__ __align__(16) u16 As[NS][128][32];
    __shared__ __align__(16) u16 Bs[NS][128][32];

    const u16* srcA[NS][2];
    const u16* srcB[NS][2];
    u16* ldsA[2];
    u16* ldsB[2];
#pragma unroll
    for (int q = 0; q < 2; ++q) {
        const int c = q * 256 + tid;
        const int rr = c >> 2;
        const int pg = (c & 3) ^ ((rr >> 1) & 3);   // swizzled global k-chunk
        const int ko = pg * 8;
        const int chunk0 = q * 256 + wave * 64;      // wave-uniform LDS chunk base
        ldsA[q] = &As[0][0][0] + (size_t)chunk0 * 8;
        ldsB[q] = &Bs[0][0][0] + (size_t)chunk0 * 8;
        int arg = rowBase + rr;
        if (EXPERT) arg = min(arg, Me - 1);
        long aRow;
        if (INDIRECT) aRow = idxl[(long)blockIdx.z * TOKENS + arg];
        else          aRow = cbase + arg;
        srcA[0][q] = Ah + aRow * (long)K + ko;
        srcB[0][q] = bth + (long)(colBase + rr) * K + ko;
        if (SPLIT) {
            srcA[NS-1][q] = Al + aRow * (long)K + ko;
            srcB[NS-1][q] = btl + (long)(colBase + rr) * K + ko;
        }
    }

    f32x4 acc[4][4];
    const f32x4 fz = {0.f, 0.f, 0.f, 0.f};
#pragma unroll
    for (int i = 0; i < 4; ++i)
#pragma unroll
        for (int j = 0; j < 4; ++j) acc[i][j] = fz;

    const int swz = (lr >> 1) & 3;   // row-dependent k-chunk swizzle for reads
    const int koA = ((quad ^ swz) * 8);

    for (int k0 = 0; k0 < K; k0 += 32) {
#pragma unroll
        for (int s = 0; s < NS; ++s)
#pragma unroll
            for (int q = 0; q < 2; ++q) {
                gld16(srcA[s][q], ldsA[q] + s * 128 * 32);
                gld16(srcB[s][q], ldsB[q] + s * 128 * 32);
                srcA[s][q] += 32; srcB[s][q] += 32;
            }
        __syncthreads();   // drains vmcnt(0): LDS tiles complete
        f16x8 af[NS][4], bfr[NS][4];
#pragma unroll
        for (int s = 0; s < NS; ++s) {
#pragma unroll
            for (int i = 0; i < 4; ++i)
                af[s][i] = *(const f16x8*)&As[s][wm*64 + i*16 + lr][koA];
#pragma unroll
            for (int j = 0; j < 4; ++j)
                bfr[s][j] = *(const f16x8*)&Bs[s][wn*64 + j*16 + lr][koA];
        }
#pragma unroll
        for (int i = 0; i < 4; ++i)
#pragma unroll
            for (int j = 0; j < 4; ++j) {
                acc[i][j] = __builtin_amdgcn_mfma_f32_16x16x32_f16(af[0][i], bfr[0][j], acc[i][j], 0, 0, 0);
                if (SPLIT) {
                    acc[i][j] = __builtin_amdgcn_mfma_f32_16x16x32_f16(af[0][i], bfr[NS-1][j], acc[i][j], 0, 0, 0);
                    acc[i][j] = __builtin_amdgcn_mfma_f32_16x16x32_f16(af[NS-1][i], bfr[0][j], acc[i][j], 0, 0, 0);
                }
            }
        __syncthreads();   // protect LDS before next iteration's staging
    }

#pragma unroll
    for (int i = 0; i < 4; ++i) {
#pragma unroll
        for (int j = 0; j < 4; ++j) {
            const int col = colBase + wn*64 + j*16 + lr;
#pragma unroll
            for (int r = 0; r < 4; ++r) {
                const int rowl = wm*64 + i*16 + quad*4 + r;
                const int grow = rowBase + rowl;
                float v = acc[i][j][r];
                if constexpr (OUTM == 3) {
                    // gate at even col, up at odd col; pair via adjacent lane
                    float p = __shfl_xor(v, 1);
                    if (EXPERT && grow >= Me) continue;
                    float g = (lr & 1) ? p : v;
                    float u = (lr & 1) ? v : p;
                    float o = g / (1.f + __expf(-g)) * u;
                    if (!(lr & 1)) {
                        const long idx = (cbase + grow) * (long)(N >> 1) + (col >> 1);
                        ((u16*)Ch)[idx] = f2h(o);
                    }
                    continue;
                }
                if (EXPERT && grow >= Me) continue;
                const long idx = (cbase + grow) * (long)N + col;
                if (ADD_RES) v += res[idx];
                if constexpr (OUTM == 0) {
                    ((float*)Ch)[idx] = v;
                } else if constexpr (OUTM == 1) {
                    ((u16*)Ch)[idx] = f2h(v);
                } else if constexpr (OUTM == 2) {
                    u16 hi, lo; split16(v, hi, lo);
                    ((u16*)Ch)[idx] = hi;
                    Cl[idx] = lo;
                }
            }
        }
    }
}

// ---------------------------------------------------------------------------
// Flash attention (causal). K from qkv (token-major), V from pre-transposed
// vt[(b,h)][d][t]. Both staged via global_load_lds w=16 into unpadded 64x64
// tiles, XOR-swizzled: LDS chunk p of row r holds global chunk p^(r&7);
// fragment reads at p=(ks*4+quad)^(lr&7) -> 2 lanes/bank-group (free).
// Split-fp16 (hi/lo) everywhere, fp32 online softmax.
// Block: 64 Q rows (4 waves x 16 rows), K/V tiles of 64. grid (32,16,2).
// qb reversed (heavy blocks first) for tail balance.
// ---------------------------------------------------------------------------
__global__ __launch_bounds__(256) void attn_k(
    const u16* __restrict__ qh_, const u16* __restrict__ ql_,
    const u16* __restrict__ vth_, const u16* __restrict__ vtl_,
    u16* __restrict__ aoh, u16* __restrict__ aol)
{
    const int qb = 31 - blockIdx.x;          // heavy first
    const int h  = blockIdx.y;
    const int b  = blockIdx.z;
    const int bh = b * NHEAD + h;
    const int tid = threadIdx.x;
    const int wave = tid >> 6, lane = tid & 63;
    const int quad = lane >> 4, lr = lane & 15;

    __shared__ __align__(16) u16 Kt[2][64][64];
    __shared__ __align__(16) u16 Vt[2][64][64];
    __shared__ __align__(16) u16 Pt[2][4][16][72];

    f16x8 qh[2], ql[2];
    {
        const size_t qoff = ((size_t)(b * SEQ + qb*64 + wave*16 + lr)) * 3072 + h * 64 + quad * 8;
        qh[0] = *(const f16x8*)(qh_ + qoff);
        qh[1] = *(const f16x8*)(qh_ + qoff + 32);
        ql[0] = *(const f16x8*)(ql_ + qoff);
        ql[1] = *(const f16x8*)(ql_ + qoff + 32);
    }
    const f32x4 fz = {0.f, 0.f, 0.f, 0.f};
    f32x4 accO[4];
#pragma unroll
    for (int nt = 0; nt < 4; ++nt) accO[nt] = fz;
    float mrow[4] = {-1e30f, -1e30f, -1e30f, -1e30f};
    float lrow[4] = {0.f, 0.f, 0.f, 0.f};
    const int ig0 = qb*64 + wave*16 + quad*4;

    // staging geometry: lane covers (row = base + lane>>3, swizzled chunk)
    const int rsub = lane >> 3;
    const int gch  = (lane & 7) ^ rsub;      // global chunk for this lane
    const int prd  = (lane >> 3) & 7;        (void)prd;

    for (int kb = 0; kb <= qb; ++kb) {
#pragma unroll
        for (int q = 0; q < 2; ++q) {
            const int row = wave*16 + q*8 + rsub;      // K: token offset; V: dim
            const size_t kaddr = ((size_t)(b * SEQ + kb*64 + row)) * 3072 + 1024 + h * 64 + gch * 8;
            const size_t vaddr = ((size_t)bh * 64 + row) * 2048 + (size_t)kb * 64 + gch * 8;
            gld16(qh_ + kaddr, &Kt[0][wave*16 + q*8][0]);
            gld16(ql_ + kaddr, &Kt[1][wave*16 + q*8][0]);
            gld16(vth_ + vaddr, &Vt[0][wave*16 + q*8][0]);
            gld16(vtl_ + vaddr, &Vt[1][wave*16 + q*8][0]);
        }
        __syncthreads();   // drains vmcnt: tiles complete

        // S = Q K^T (split product: hh + hl + lh)
        f32x4 accS[4];
#pragma unroll
        for (int nt = 0; nt < 4; ++nt) accS[nt] = fz;
#pragma unroll
        for (int ks = 0; ks < 2; ++ks) {
#pragma unroll
            for (int nt = 0; nt < 4; ++nt) {
                const int p = (ks*4 + quad) ^ (lr & 7);
                f16x8 kh = *(const f16x8*)&Kt[0][nt*16 + lr][p*8];
                f16x8 kl = *(const f16x8*)&Kt[1][nt*16 + lr][p*8];
                accS[nt] = __builtin_amdgcn_mfma_f32_16x16x32_f16(qh[ks], kh, accS[nt], 0, 0, 0);
                accS[nt] = __builtin_amdgcn_mfma_f32_16x16x32_f16(qh[ks], kl, accS[nt], 0, 0, 0);
                accS[nt] = __builtin_amdgcn_mfma_f32_16x16x32_f16(ql[ks], kh, accS[nt], 0, 0, 0);
            }
        }

        // scale + causal mask + online softmax (fp32)
        float pv[4][4];
        float mx[4] = {-1e30f, -1e30f, -1e30f, -1e30f};
        const bool diag = (kb == qb);
#pragma unroll
        for (int nt = 0; nt < 4; ++nt) {
            const int jg = kb*64 + nt*16 + lr;
#pragma unroll
            for (int r = 0; r < 4; ++r) {
                float s = accS[nt][r] * 0.125f;
                if (diag && jg > ig0 + r) s = -1e30f;
                pv[nt][r] = s;
                mx[r] = fmaxf(mx[r], s);
            }
        }
#pragma unroll
        for (int off = 1; off < 16; off <<= 1)
#pragma unroll
            for (int r = 0; r < 4; ++r) mx[r] = fmaxf(mx[r], __shfl_xor(mx[r], off));
        float alpha[4];
#pragma unroll
        for (int r = 0; r < 4; ++r) {
            float mn = fmaxf(mrow[r], mx[r]);
            alpha[r] = __expf(mrow[r] - mn);
            mrow[r] = mn;
        }
        float rs[4] = {0.f, 0.f, 0.f, 0.f};
#pragma unroll
        for (int nt = 0; nt < 4; ++nt)
#pragma unroll
            for (int r = 0; r < 4; ++r) {
                float p = __expf(pv[nt][r] - mrow[r]);
                pv[nt][r] = p;
                rs[r] += p;
            }
#pragma unroll
        for (int off = 1; off < 16; off <<= 1)
#pragma unroll
            for (int r = 0; r < 4; ++r) rs[r] += __shfl_xor(rs[r], off);
#pragma unroll
        for (int r = 0; r < 4; ++r) lrow[r] = lrow[r] * alpha[r] + rs[r];
#pragma unroll
        for (int nt = 0; nt < 4; ++nt)
#pragma unroll
            for (int r = 0; r < 4; ++r) accO[nt][r] *= alpha[r];

        // P (C-layout) -> LDS, split hi/lo, for A-operand reads
#pragma unroll
        for (int nt = 0; nt < 4; ++nt)
#pragma unroll
            for (int r = 0; r < 4; ++r) {
                u16 hi, lo; split16(pv[nt][r], hi, lo);
                Pt[0][wave][quad*4 + r][nt*16 + lr] = hi;
                Pt[1][wave][quad*4 + r][nt*16 + lr] = lo;
            }
        __syncthreads();

        // O += P V
#pragma unroll
        for (int ks = 0; ks < 2; ++ks) {
            f16x8 ph = *(const f16x8*)&Pt[0][wave][lr][ks*32 + quad*8];
            f16x8 pl = *(const f16x8*)&Pt[1][wave][lr][ks*32 + quad*8];
#pragma unroll
            for (int nt = 0; nt < 4; ++nt) {
                const int p = (ks*4 + quad) ^ (lr & 7);
                f16x8 vh = *(const f16x8*)&Vt[0][nt*16 + lr][p*8];
                f16x8 vl = *(const f16x8*)&Vt[1][nt*16 + lr][p*8];
                accO[nt] = __builtin_amdgcn_mfma_f32_16x16x32_f16(ph, vh, accO[nt], 0, 0, 0);
                accO[nt] = __builtin_amdgcn_mfma_f32_16x16x32_f16(ph, vl, accO[nt], 0, 0, 0);
                accO[nt] = __builtin_amdgcn_mfma_f32_16x16x32_f16(pl, vh, accO[nt], 0, 0, 0);
            }
        }
        __syncthreads();   // all reads done before next staging
    }

#pragma unroll
    for (int nt = 0; nt < 4; ++nt)
#pragma unroll
        for (int r = 0; r < 4; ++r) {
            const int t = ig0 + r;
            float o = accO[nt][r] / lrow[r];
            u16 hi, lo; split16(o, hi, lo);
            const size_t idx = ((size_t)(b * SEQ + t)) * DMODEL + h * 64 + nt*16 + lr;
            aoh[idx] = hi;
            aol[idx] = lo;
        }
}

// ---------------------------------------------------------------------------
// Router with inline RMSNorm: reads x1 fp32, computes rmsnorm(x1)*fnw in fp32,
// fp32 logits, top-2, normalized gates, per-expert token lists. 1 wave/token.
// ---------------------------------------------------------------------------
__global__ __launch_bounds__(64) void router_k(
    const float* __restrict__ x1, const float* __restrict__ fnw,
    const float* __restrict__ rw,
    int* __restrict__ count, int* __restrict__ tokE, int* __restrict__ tokP,
    float* __restrict__ tokG, int* __restrict__ idxl)
{
    const int t = blockIdx.x;
    const int lane = threadIdx.x;
    const float* xr = x1 + (size_t)t * DMODEL;
    float4 xv[4];
    float ss = 0.f;
#pragma unroll
    for (int it = 0; it < 4; ++it) {
        xv[it] = *(const float4*)(xr + (it * 64 + lane) * 4);
        ss += xv[it].x*xv[it].x + xv[it].y*xv[it].y + xv[it].z*xv[it].z + xv[it].w*xv[it].w;
    }
#pragma unroll
    for (int off = 32; off; off >>= 1) ss += __shfl_xor(ss, off);
    const float rms = rsqrtf(ss * (1.0f / DMODEL) + 1e-6f);

    float acc[NEXP];
#pragma unroll
    for (int e = 0; e < NEXP; ++e) acc[e] = 0.f;
#pragma unroll
    for (int it = 0; it < 4; ++it) {
        const int d0 = (it * 64 + lane) * 4;
        float4 wv = *(const float4*)(fnw + d0);
        float hvv[4] = {xv[it].x * rms * wv.x, xv[it].y * rms * wv.y,
                        xv[it].z * rms * wv.z, xv[it].w * rms * wv.w};
#pragma unroll
        for (int k = 0; k < 4; ++k) {
            const float* r = rw + (size_t)(d0 + k) * NEXP;
            float4 r0 = *(const float4*)(r);
            float4 r1 = *(const float4*)(r + 4);
            acc[0] += hvv[k] * r0.x; acc[1] += hvv[k] * r0.y;
            acc[2] += hvv[k] * r0.z; acc[3] += hvv[k] * r0.w;
            acc[4] += hvv[k] * r1.x; acc[5] += hvv[k] * r1.y;
            acc[6] += hvv[k] * r1.z; acc[7] += hvv[k] * r1.w;
        }
    }
#pragma unroll
    for (int e = 0; e < NEXP; ++e)
#pragma unroll
        for (int off = 32; off; off >>= 1) acc[e] += __shfl_down(acc[e], off);
    if (lane == 0) {
        int e0 = 0; float v0 = acc[0];
#pragma unroll
        for (int e = 1; e < NEXP; ++e) if (acc[e] > v0) { v0 = acc[e]; e0 = e; }
        int e1 = -1; float v1 = -3.4e38f;
#pragma unroll
        for (int e = 0; e < NEXP; ++e) if (e != e0 && acc[e] > v1) { v1 = acc[e]; e1 = e; }
        const float rexp = __expf(v1 - v0);
        const float g0 = 1.f / (1.f + rexp);
        const float g1 = rexp * g0;
        const int p0 = atomicAdd(&count[e0], 1);
        const int p1 = atomicAdd(&count[e1], 1);
        idxl[e0 * TOKENS + p0] = t;
        idxl[e1 * TOKENS + p1] = t;
        tokE[2*t] = e0; tokE[2*t + 1] = e1;
        tokP[2*t] = p0; tokP[2*t + 1] = p1;
        tokG[2*t] = g0; tokG[2*t + 1] = g1;
    }
}

__global__ void prefix_k(const int* __restrict__ count, int* __restrict__ base)
{
    if (threadIdx.x == 0) {
        int s = 0;
#pragma unroll
        for (int e = 0; e < NEXP; ++e) { base[e] = s; s += count[e]; }
    }
}

// out[t] = x1[t] + g0*y[slot0] + g1*y[slot1]; plus aux_loss = 0
__global__ __launch_bounds__(256) void combine_k(
    const float* __restrict__ x1, const u16* __restrict__ y,
    const int* __restrict__ tokE, const int* __restrict__ tokP,
    const float* __restrict__ tokG, const int* __restrict__ base,
    float* __restrict__ out)
{
    const int t = blockIdx.x;
    const int d = threadIdx.x * 4;
    const int e0 = tokE[2*t], e1 = tokE[2*t + 1];
    const int s0 = base[e0] + tokP[2*t], s1 = base[e1] + tokP[2*t + 1];
    const float g0 = tokG[2*t], g1 = tokG[2*t + 1];
    float4 xv = *(const float4*)(x1 + (size_t)t * DMODEL + d);
    u16 y0[4], y1[4];
    *(uint2*)y0 = *(const uint2*)(y + (size_t)s0 * DMODEL + d);
    *(uint2*)y1 = *(const uint2*)(y + (size_t)s1 * DMODEL + d);
    float4 o;
    o.x = xv.x + g0 * h2f(y0[0]) + g1 * h2f(y1[0]);
    o.y = xv.y + g0 * h2f(y0[1]) + g1 * h2f(y1[1]);
    o.z = xv.z + g0 * h2f(y0[2]) + g1 * h2f(y1[2]);
    o.w = xv.w + g0 * h2f(y0[3]) + g1 * h2f(y1[3]);
    *(float4*)(out + (size_t)t * DMODEL + d) = o;
    if (t == 0 && threadIdx.x == 0) out[(size_t)TOKENS * DMODEL] = 0.f;  // aux_loss (AUX_COEFF=0)
}

// ---------------------------------------------------------------------------
// Workspace arena (121 MB total), lifetime-overlaid:
//   [0,1)      ctl: counts/bases/tokE/tokP/tokG/idxl
//   [1,65)     hh(1-9) hl(9-17) qkvh(17-41) qkvl(41-65)
//                -> w13t(1-65) after attn
//                -> w2t(1-33) + yb(33-49) after MoE GEMM1
//   [65,97)    aoh(65-73) aol(73-81) qkvwt_h(81-87) qkvwt_l(87-93)
//              wo_h(93-95) wo_l(95-97)   -> upb(65-97) after out-proj
//   [97,113)   vth(97-105) vtl(105-113) during attn -> x1 (fp32) after
//   [113,121)  hnb (fp16 rmsnorm2, written after attn, until GEMM1)
// ---------------------------------------------------------------------------
extern "C" void kernel_launch(void* const* d_in, const int* in_sizes, int n_in,
                              void* d_out, int out_size, void* d_ws, size_t ws_size,
                              hipStream_t stream)
{
    const float* x     = (const float*)d_in[0];
    const float* anw   = (const float*)d_in[1];
    const float* fnw   = (const float*)d_in[2];
    const float* qkv_w = (const float*)d_in[3];
    const float* out_w = (const float*)d_in[4];
    const float* rw    = (const float*)d_in[5];
    const float* w1    = (const float*)d_in[6];
    const float* w3    = (const float*)d_in[7];
    const float* w2    = (const float*)d_in[8];
    float* out = (float*)d_out;

    char* W = (char*)d_ws;
    const size_t MB = 1ull << 20;
    int*   counts = (int*)(W);
    int*   bases  = (int*)(W + 256);
    int*   tokE   = (int*)(W + 1024);
    int*   tokP   = (int*)(W + 1024 + 33*1024);
    float* tokG   = (float*)(W + 1024 + 66*1024);
    int*   idxl   = (int*)(W + 1024 + 99*1024);

    u16* hh      = (u16*)(W + 1*MB);
    u16* hl      = (u16*)(W + 9*MB);
    u16* qkvh    = (u16*)(W + 17*MB);
    u16* qkvl    = (u16*)(W + 41*MB);
    u16* aoh     = (u16*)(W + 65*MB);
    u16* aol     = (u16*)(W + 73*MB);
    u16* qkvwt_h = (u16*)(W + 81*MB);
    u16* qkvwt_l = (u16*)(W + 87*MB);
    u16* wo_h    = (u16*)(W + 93*MB);
    u16* wo_l    = (u16*)(W + 95*MB);
    u16* vth     = (u16*)(W + 97*MB);   // 8 MB, during attention
    u16* vtl     = (u16*)(W + 105*MB);  // 8 MB, during attention
    float* x1    = (float*)(W + 97*MB); // 16 MB, after attention (vt dead)
    u16* hnb     = (u16*)(W + 113*MB);
    u16* w13t    = (u16*)(W + 1*MB);    // 64 MB, after attn
    u16* upb     = (u16*)(W + 65*MB);   // 32 MB, after out-proj
    u16* w2t     = (u16*)(W + 1*MB);    // 32 MB, after GEMM1
    u16* yb      = (u16*)(W + 33*MB);   // 16 MB, after GEMM1

    hipMemsetAsync(counts, 0, NEXP * 4, stream);

    // attn-path weight prep: transpose + split-cast
    transpose_cast<true ><<<dim3(96, 32, 1), 256, 0, stream>>>(qkv_w, qkvwt_h, qkvwt_l, 1024, 3072, 0, 0, 1, 0);
    transpose_cast<true ><<<dim3(32, 32, 1), 256, 0, stream>>>(out_w, wo_h, wo_l, 1024, 1024, 0, 0, 1, 0);

    // attention path (split-fp16 ~ fp32 quality; router selection depends on it)
    rmsnorm_k<<<TOKENS, 256, 0, stream>>>(x, anw, hh, hl);
    gemm_bt<true, 2, false, false, false><<<dim3(24, 32, 1), 256, 0, stream>>>(
        hh, hl, qkvwt_h, qkvwt_l, qkvh, qkvl, nullptr, TOKENS, 3072, 1024, 0, nullptr, nullptr, nullptr);
    vtrans_k<<<dim3(64, 2, 32), 256, 0, stream>>>(qkvh, qkvl, vth, vtl);
    attn_k<<<dim3(32, 16, 2), 256, 0, stream>>>(qkvh, qkvl, vth, vtl, aoh, aol);

    // MoE weight prep into [1,65) — hh/hl/qkvh/qkvl are dead now.
    // Interleave: w1 col f -> row 2f (gate), w3 col f -> row 2f+1 (up).
    transpose_cast<false><<<dim3(64, 32, 8), 256, 0, stream>>>(w1, w13t, nullptr, 1024, 2048, 2048L*1024, 4096L*1024, 2, 0);
    transpose_cast<false><<<dim3(64, 32, 8), 256, 0, stream>>>(w3, w13t, nullptr, 1024, 2048, 2048L*1024, 4096L*1024, 2, 1);

    // out-proj + residual -> x1 (fp32)
    gemm_bt<true, 0, true, false, false><<<dim3(8, 32, 1), 256, 0, stream>>>(
        aoh, aol, wo_h, wo_l, x1, nullptr, x, TOKENS, 1024, 1024, 0, nullptr, nullptr, nullptr);

    // rmsnorm2 (fp16 for MoE) + fp32 router (inline rmsnorm)
    rmsnorm_k<<<TOKENS, 256, 0, stream>>>(x1, fnw, hnb, nullptr);
    router_k<<<TOKENS, 64, 0, stream>>>(x1, fnw, rw, counts, tokE, tokP, tokG, idxl);
    prefix_k<<<1, 64, 0, stream>>>(counts, bases);

    // MoE GEMM1 fused silu: (hnb gather) @ w13t -> upb (fp16, [slot][2048])
    gemm_bt<false, 3, false, true, true><<<dim3(32, 32, 8), 256, 0, stream>>>(
        hnb, nullptr, w13t, nullptr, upb, nullptr, nullptr, TOKENS, 4096, 1024, 4096L*1024, counts, bases, idxl);

    // w2 transpose into [1,33) — w13t dead now
    transpose_cast<false><<<dim3(32, 64, 8), 256, 0, stream>>>(w2, w2t, nullptr, 2048, 1024, 2048L*1024, 1024L*2048, 1, 0);

    // MoE GEMM2: upb @ w2t -> yb (fp16)
    gemm_bt<false, 1, false, true, false><<<dim3(8, 32, 8), 256, 0, stream>>>(
        upb, nullptr, w2t, nullptr, yb, nullptr, nullptr, TOKENS, 1024, 2048, 1024L*2048, counts, bases, idxl);

    combine_k<<<TOKENS, 256, 0, stream>>>(x1, yb, tokE, tokP, tokG, bases, out);
}